// Round 8
// baseline (62.185 us; speedup 1.0000x reference)
//
#include <hip/hip_runtime.h>
#include <hip/hip_bf16.h>

typedef __attribute__((ext_vector_type(4))) float f32x4;
typedef __attribute__((ext_vector_type(4))) short s16x4;
typedef __attribute__((ext_vector_type(8))) short s16x8;

#define NB 8
#define NC 16
#define HH 512
#define WW 512
// l = Hp*64 + Wp (4096), l' = hp*8 + wp (64), m = c*64 + kh*8 + kw (1024)

// ---------- K1: fused 8x8 avg-pool (-> bt) + attn normalize (-> abf bf16) ----------
// x and attn are read-once -> nontemporal loads (keep L2 for bt/abf, which the
// gemm kernel DMA-reads next). bt/abf writes stay cached (small, reused).
__global__ __launch_bounds__(256) void prep(const float* __restrict__ x,
                                            const float* __restrict__ attn,
                                            __hip_bfloat16* __restrict__ bt,
                                            __hip_bfloat16* __restrict__ abf) {
    int flat = blockIdx.x * 256 + threadIdx.x;      // 0..524287
    // ---- pool: bt[b][m][l'] ----
    {
        int wq = flat & 63;                          // lane-consecutive -> coalesced
        int hq = (flat >> 6) & 63;
        int c  = (flat >> 12) & 15;
        int b  = flat >> 16;
        const float* base = x + ((size_t)(b * NC + c) * HH + hq * 8) * WW + wq * 8;
        float s = 0.f;
#pragma unroll
        for (int r = 0; r < 8; ++r) {
            f32x4 v0 = __builtin_nontemporal_load((const f32x4*)(base + (size_t)r * WW));
            f32x4 v1 = __builtin_nontemporal_load((const f32x4*)(base + (size_t)r * WW + 4));
            s += v0[0] + v0[1] + v0[2] + v0[3] + v1[0] + v1[1] + v1[2] + v1[3];
        }
        s *= (1.f / 64.f);
        int m  = c * 64 + (hq & 7) * 8 + (wq & 7);   // (c, kh, kw)
        int lp = (hq >> 3) * 8 + (wq >> 3);          // (hp, wp)
        bt[((size_t)b * 1024 + m) * 64 + lp] = __float2bfloat16(s);
    }
    // ---- attn: abf[row][:] = bf16(attn_row * 1/(nnz+1e-5)); 16 lanes own a row ----
    {
        int row   = flat >> 4;                       // 0..32767 over [8][4096]
        int chunk = flat & 15;                       // 4 floats each
        f32x4 v = __builtin_nontemporal_load((const f32x4*)(attn + (size_t)row * 64 + chunk * 4));
        int cnt = (v[0] != 0.f) + (v[1] != 0.f) + (v[2] != 0.f) + (v[3] != 0.f);
        cnt += __shfl_xor(cnt, 1);
        cnt += __shfl_xor(cnt, 2);
        cnt += __shfl_xor(cnt, 4);
        cnt += __shfl_xor(cnt, 8);                   // row total across its 16 owner lanes
        float inv = 1.0f / ((float)cnt + 1e-5f);
        s16x4 o;
#pragma unroll
        for (int e = 0; e < 4; ++e) {
            __hip_bfloat16 h = __float2bfloat16(v[e] * inv);
            o[e] = (short)*reinterpret_cast<unsigned short*>(&h);
        }
        *(s16x4*)((unsigned short*)abf + (size_t)row * 64 + chunk * 4) = o;
    }
}

// ---------- K2: pure-DMA GEMM + fold-scatter ----------
// Both tiles [128][64] bf16 in LDS, chunk-XOR swizzled (phys 16B chunk p of row r
// holds logical chunk p^(r&7)); filled by global_load_lds with the inverse swizzle
// on the GLOBAL source address (LDS dest linear) — R5-verified pattern.
// MFMA roles: A-operand rows = m (Bs), B-operand rows = l (As) => D col(lane&15)=l,
// D row((lane>>4)*4+r)=m => f32x4 store of 4 consecutive kw. out is write-once ->
// nontemporal stores keep L2 serving the abf/bt DMA traffic.
__global__ __launch_bounds__(256, 5) void gemm_scatter(const __hip_bfloat16* __restrict__ abf,
                                                       const __hip_bfloat16* __restrict__ bt,
                                                       float* __restrict__ out) {
    int mb = blockIdx.x;     // 0..7   m-tile (fastest: attn-tile sharers adjacent)
    int lb = blockIdx.y;     // 0..31  l-tile
    int b  = blockIdx.z;     // 0..7

    __shared__ __align__(16) unsigned short As[128][64];
    __shared__ __align__(16) unsigned short Bs[128][64];

    int tid = threadIdx.x;

    // stage both tiles: 2048 16B chunks via async DMA, pre-swizzled sources
    {
        const unsigned short* Ag = (const unsigned short*)abf + ((size_t)b * 4096 + lb * 128) * 64;
        const unsigned short* Bg = (const unsigned short*)bt  + ((size_t)b * 1024 + mb * 128) * 64;
#pragma unroll
        for (int i = 0; i < 4; ++i) {
            int cid = tid + i * 256;          // 0..1023
            int row = cid >> 3, p = cid & 7;
            int src = row * 64 + (p ^ (row & 7)) * 8;
            __builtin_amdgcn_global_load_lds(
                (const __attribute__((address_space(1))) void*)(Ag + src),
                (__attribute__((address_space(3))) void*)(&As[0][0] + (size_t)cid * 8),
                16, 0, 0);
            __builtin_amdgcn_global_load_lds(
                (const __attribute__((address_space(1))) void*)(Bg + src),
                (__attribute__((address_space(3))) void*)(&Bs[0][0] + (size_t)cid * 8),
                16, 0, 0);
        }
    }
    __syncthreads();   // drains DMA (vmcnt 0) + joins block

    int w    = tid >> 6;
    int lane = tid & 63;
    int wm   = (w & 1) * 64;      // wave m-base in tile
    int wl   = (w >> 1) * 64;     // wave l-base in tile
    int lr   = lane & 15;
    int kq   = lane >> 4;
    int sw   = lr & 7;

    f32x4 acc[4][4] = {};         // [mi][lj]
#pragma unroll
    for (int ks = 0; ks < 2; ++ks) {                // K = 64 = 2 x 32
        int p = (ks * 4 + kq) ^ sw;                 // swizzled 16B chunk index
        s16x8 mf[4], lf[4];
#pragma unroll
        for (int i = 0; i < 4; ++i)
            mf[i] = *(const s16x8*)&Bs[wm + i * 16 + lr][p * 8];
#pragma unroll
        for (int j = 0; j < 4; ++j)
            lf[j] = *(const s16x8*)&As[wl + j * 16 + lr][p * 8];
#pragma unroll
        for (int i = 0; i < 4; ++i)
#pragma unroll
            for (int j = 0; j < 4; ++j)
                acc[i][j] = __builtin_amdgcn_mfma_f32_16x16x32_bf16(mf[i], lf[j], acc[i][j], 0, 0, 0);
    }

    // epilogue: nontemporal f32x4 stores; 4 consecutive m == 4 consecutive kw
#pragma unroll
    for (int mi = 0; mi < 4; ++mi) {
        int m0 = mb * 128 + wm + mi * 16 + kq * 4;  // multiple of 4
        int c  = m0 >> 6, kh = (m0 >> 3) & 7, kw = m0 & 7;   // kw in {0,4}
        float* obase = out + (((size_t)(b * NC + c) * HH) + kh) * WW + kw;
#pragma unroll
        for (int lj = 0; lj < 4; ++lj) {
            int l  = lb * 128 + wl + lj * 16 + lr;
            int Hp = l >> 6, Wp = l & 63;
            __builtin_nontemporal_store(acc[mi][lj],
                                        (f32x4*)(obase + ((size_t)Hp * 8) * WW + Wp * 8));
        }
    }
}

extern "C" void kernel_launch(void* const* d_in, const int* in_sizes, int n_in,
                              void* d_out, int out_size, void* d_ws, size_t ws_size,
                              hipStream_t stream) {
    const float* x    = (const float*)d_in[0];
    const float* attn = (const float*)d_in[1];
    float* out        = (float*)d_out;

    __hip_bfloat16* bt  = (__hip_bfloat16*)d_ws;                        // 1 MB: [8][1024][64]
    __hip_bfloat16* abf = (__hip_bfloat16*)((char*)d_ws + (1 << 20));   // 4 MB: [8][4096][64]

    prep<<<2048, 256, 0, stream>>>(x, attn, bt, abf);
    dim3 grid(8, 32, 8);
    gemm_scatter<<<grid, 256, 0, stream>>>(abf, bt, out);
}

// Round 9
// 54.205 us; speedup vs baseline: 1.1472x; 1.1472x over previous
//
#include <hip/hip_runtime.h>
#include <hip/hip_bf16.h>

typedef __attribute__((ext_vector_type(4))) float f32x4;
typedef __attribute__((ext_vector_type(4))) short s16x4;
typedef __attribute__((ext_vector_type(8))) short s16x8;

#define NB 8
#define NC 16
#define HH 512
#define WW 512
// l = Hp*64 + Wp (4096), l' = hp*8 + wp (64), m = c*64 + kh*8 + kw (1024)

// ---------- K1: fused 8x8 avg-pool (-> bt) + attn normalize (-> abf bf16) ----------
// Both parts memory-independent; the 12 MB attn stream hides inside the 128 MB x read.
__global__ __launch_bounds__(256) void prep(const float* __restrict__ x,
                                            const float* __restrict__ attn,
                                            __hip_bfloat16* __restrict__ bt,
                                            __hip_bfloat16* __restrict__ abf) {
    int flat = blockIdx.x * 256 + threadIdx.x;      // 0..524287
    // ---- pool: bt[b][m][l'] ----
    {
        int wq = flat & 63;                          // lane-consecutive -> coalesced
        int hq = (flat >> 6) & 63;
        int c  = (flat >> 12) & 15;
        int b  = flat >> 16;
        const float* base = x + ((size_t)(b * NC + c) * HH + hq * 8) * WW + wq * 8;
        float s = 0.f;
#pragma unroll
        for (int r = 0; r < 8; ++r) {
            f32x4 v0 = *(const f32x4*)(base + (size_t)r * WW);
            f32x4 v1 = *(const f32x4*)(base + (size_t)r * WW + 4);
            s += v0[0] + v0[1] + v0[2] + v0[3] + v1[0] + v1[1] + v1[2] + v1[3];
        }
        s *= (1.f / 64.f);
        int m  = c * 64 + (hq & 7) * 8 + (wq & 7);   // (c, kh, kw)
        int lp = (hq >> 3) * 8 + (wq >> 3);          // (hp, wp)
        bt[((size_t)b * 1024 + m) * 64 + lp] = __float2bfloat16(s);
    }
    // ---- attn: abf[row][:] = bf16(attn_row * 1/(nnz+1e-5)); 16 lanes own a row ----
    {
        int row   = flat >> 4;                       // 0..32767 over [8][4096]
        int chunk = flat & 15;                       // 4 floats each
        f32x4 v = *(const f32x4*)(attn + (size_t)row * 64 + chunk * 4);
        int cnt = (v[0] != 0.f) + (v[1] != 0.f) + (v[2] != 0.f) + (v[3] != 0.f);
        cnt += __shfl_xor(cnt, 1);
        cnt += __shfl_xor(cnt, 2);
        cnt += __shfl_xor(cnt, 4);
        cnt += __shfl_xor(cnt, 8);                   // row total across its 16 owner lanes
        float inv = 1.0f / ((float)cnt + 1e-5f);
        s16x4 o;
#pragma unroll
        for (int e = 0; e < 4; ++e) {
            __hip_bfloat16 h = __float2bfloat16(v[e] * inv);
            o[e] = (short)*reinterpret_cast<unsigned short*>(&h);
        }
        *(s16x4*)((unsigned short*)abf + (size_t)row * 64 + chunk * 4) = o;
    }
}

// ---------- K2: pure-DMA GEMM + fold-scatter, 2 m-tiles per block ----------
// Tiles [128][64] bf16 in LDS, chunk-XOR swizzled (phys 16B chunk p of row r holds
// logical chunk p^(r&7)); filled by global_load_lds with the inverse swizzle on the
// GLOBAL source address (LDS dest linear) — R5/R7-verified pattern. One block stages
// As + Bs[0] + Bs[1] (12 DMA issues), drains ONCE, then computes/stores both m-tiles
// reusing As. 48 KB LDS -> 3 blocks/CU; post-barrier phase is write-stream-bound.
// MFMA roles: A-operand rows = m (Bs), B-operand rows = l (As) => D col(lane&15)=l,
// D row((lane>>4)*4+r)=m => f32x4 store of 4 consecutive kw.
__global__ __launch_bounds__(256, 3) void gemm_scatter(const __hip_bfloat16* __restrict__ abf,
                                                       const __hip_bfloat16* __restrict__ bt,
                                                       float* __restrict__ out) {
    int mbp = blockIdx.x;    // 0..3   m-tile pair
    int lb  = blockIdx.y;    // 0..31  l-tile
    int b   = blockIdx.z;    // 0..7

    __shared__ __align__(16) unsigned short As[128][64];
    __shared__ __align__(16) unsigned short Bs[2][128][64];

    int tid = threadIdx.x;

    // stage all three tiles: 3072 16B chunks via async DMA, pre-swizzled sources
    {
        const unsigned short* Ag = (const unsigned short*)abf + ((size_t)b * 4096 + lb * 128) * 64;
        const unsigned short* Bg = (const unsigned short*)bt  + ((size_t)b * 1024 + mbp * 256) * 64;
#pragma unroll
        for (int i = 0; i < 4; ++i) {
            int cid = tid + i * 256;          // 0..1023
            int row = cid >> 3, p = cid & 7;
            int src = row * 64 + (p ^ (row & 7)) * 8;
            __builtin_amdgcn_global_load_lds(
                (const __attribute__((address_space(1))) void*)(Ag + src),
                (__attribute__((address_space(3))) void*)(&As[0][0] + (size_t)cid * 8),
                16, 0, 0);
            __builtin_amdgcn_global_load_lds(
                (const __attribute__((address_space(1))) void*)(Bg + src),
                (__attribute__((address_space(3))) void*)(&Bs[0][0][0] + (size_t)cid * 8),
                16, 0, 0);
            __builtin_amdgcn_global_load_lds(
                (const __attribute__((address_space(1))) void*)(Bg + 128 * 64 + src),
                (__attribute__((address_space(3))) void*)(&Bs[1][0][0] + (size_t)cid * 8),
                16, 0, 0);
        }
    }
    __syncthreads();   // drains DMA (vmcnt 0) + joins block — once per block

    int w    = tid >> 6;
    int lane = tid & 63;
    int wm   = (w & 1) * 64;      // wave m-base in tile
    int wl   = (w >> 1) * 64;     // wave l-base in tile
    int lr   = lane & 15;
    int kq   = lane >> 4;
    int sw   = lr & 7;

#pragma unroll
    for (int t = 0; t < 2; ++t) {
        int mb = mbp * 2 + t;

        f32x4 acc[4][4] = {};     // [mi][lj]
#pragma unroll
        for (int ks = 0; ks < 2; ++ks) {            // K = 64 = 2 x 32
            int p = (ks * 4 + kq) ^ sw;             // swizzled 16B chunk index
            s16x8 mf[4], lf[4];
#pragma unroll
            for (int i = 0; i < 4; ++i)
                mf[i] = *(const s16x8*)&Bs[t][wm + i * 16 + lr][p * 8];
#pragma unroll
            for (int j = 0; j < 4; ++j)
                lf[j] = *(const s16x8*)&As[wl + j * 16 + lr][p * 8];
#pragma unroll
            for (int i = 0; i < 4; ++i)
#pragma unroll
                for (int j = 0; j < 4; ++j)
                    acc[i][j] = __builtin_amdgcn_mfma_f32_16x16x32_bf16(mf[i], lf[j],
                                                                        acc[i][j], 0, 0, 0);
        }

        // epilogue: f32x4 stores; 4 consecutive m == 4 consecutive kw
#pragma unroll
        for (int mi = 0; mi < 4; ++mi) {
            int m0 = mb * 128 + wm + mi * 16 + kq * 4;   // multiple of 4
            int c  = m0 >> 6, kh = (m0 >> 3) & 7, kw = m0 & 7;   // kw in {0,4}
            float* obase = out + (((size_t)(b * NC + c) * HH) + kh) * WW + kw;
#pragma unroll
            for (int lj = 0; lj < 4; ++lj) {
                int l  = lb * 128 + wl + lj * 16 + lr;
                int Hp = l >> 6, Wp = l & 63;
                *(f32x4*)(obase + ((size_t)Hp * 8) * WW + Wp * 8) = acc[mi][lj];
            }
        }
    }
}

extern "C" void kernel_launch(void* const* d_in, const int* in_sizes, int n_in,
                              void* d_out, int out_size, void* d_ws, size_t ws_size,
                              hipStream_t stream) {
    const float* x    = (const float*)d_in[0];
    const float* attn = (const float*)d_in[1];
    float* out        = (float*)d_out;

    __hip_bfloat16* bt  = (__hip_bfloat16*)d_ws;                        // 1 MB: [8][1024][64]
    __hip_bfloat16* abf = (__hip_bfloat16*)((char*)d_ws + (1 << 20));   // 4 MB: [8][4096][64]

    prep<<<2048, 256, 0, stream>>>(x, attn, bt, abf);
    dim3 grid(4, 32, 8);
    gemm_scatter<<<grid, 256, 0, stream>>>(abf, bt, out);
}